// Round 2
// baseline (193.327 us; speedup 1.0000x reference)
//
#include <hip/hip_runtime.h>

// B=8, L=512, K=512, D=M=N=P=64, all fp32.
// ws: vkc = 8*512*64 floats (1 MB).

// ---------------------------------------------------------------------------
// K1 (proven, ~6.2 TB/s): vkc[b,k,n] = sum_p vk[b,k,p,n] * vexp[b,k,p]
// ---------------------------------------------------------------------------
__global__ __launch_bounds__(256) void vkc_kernel(const float* __restrict__ vk,
                                                  const float* __restrict__ vexp,
                                                  float* __restrict__ vkc) {
    const int wave = (blockIdx.x << 2) + (threadIdx.x >> 6);  // b*512 + k
    const int lane = threadIdx.x & 63;

    const float ve_reg = vexp[wave * 64 + lane];
    const int n0 = (lane & 15) << 2;
    const float* base = vk + (long)wave * 4096;

    float ax = 0.f, ay = 0.f, az = 0.f, aw = 0.f;
    #pragma unroll
    for (int it = 0; it < 16; ++it) {
        const int p = (lane >> 4) + (it << 2);
        const float4 v4 = *(const float4*)(base + p * 64 + n0);
        const float w = __shfl(ve_reg, p, 64);
        ax += v4.x * w; ay += v4.y * w; az += v4.z * w; aw += v4.w * w;
    }
    ax += __shfl_down(ax, 32, 64); ax += __shfl_down(ax, 16, 64);
    ay += __shfl_down(ay, 32, 64); ay += __shfl_down(ay, 16, 64);
    az += __shfl_down(az, 32, 64); az += __shfl_down(az, 16, 64);
    aw += __shfl_down(aw, 32, 64); aw += __shfl_down(aw, 16, 64);

    if ((lane & 48) == 0) {
        float4 r; r.x = ax; r.y = ay; r.z = az; r.w = aw;
        *(float4*)(vkc + wave * 64 + n0) = r;
    }
}

// LDS-only barrier: drain LDS (lgkmcnt) but keep global loads (vmcnt) in
// flight across the barrier. All inter-phase deps below are LDS-only, so
// this is sufficient; the hoisted vq loads stay outstanding (T4/T14).
__device__ __forceinline__ void lds_barrier() {
    asm volatile("s_waitcnt lgkmcnt(0)" ::: "memory");
    __builtin_amdgcn_s_barrier();
}

// ---------------------------------------------------------------------------
// K2+K3 fused: per (batch, 8 l-rows), 512 threads:
//   [phase 0: issue vq loads]  scores -> softmax -> tmp (LDS) -> vq.tmp
//   -> residual + LN -> out
// vq (67 MB, the dominant HBM traffic) is issued at kernel start and
// consumed in phase 5 — its latency hides under phases 1-4.
// ---------------------------------------------------------------------------
__global__ __launch_bounds__(512, 4) void score_out_kernel(
        const float* __restrict__ q,
        const float* __restrict__ k,
        const float* __restrict__ vkc,
        const float* __restrict__ scale_p,
        const float* __restrict__ vq,
        const float* __restrict__ gamma,
        const float* __restrict__ beta,
        float* __restrict__ out) {
    __shared__ float sc[8][512];          // 16 KB
    __shared__ float tp[8][8][64];        // 16 KB
    __shared__ float tmp_s[8][64];        // 2 KB
    __shared__ float attn_s[8][64];       // 2 KB

    const int t = threadIdx.x;
    const int wv = t >> 6;
    const int lane = t & 63;
    const int batch = blockIdx.x >> 6;
    const int l0 = (blockIdx.x & 63) << 3;

    // ---- phase 0: issue the phase-5 global loads NOW (T14 issue-early) ----
    const int row = batch * 512 + l0 + wv;         // this wave's output row
    const float* vql = vq + (long)row * 4096;
    float4 v[16];
    #pragma unroll
    for (int it = 0; it < 16; ++it)
        v[it] = *(const float4*)(vql + it * 256 + lane * 4);
    const float qv = q[row * 64 + lane];

    const float scale = scale_p[0];
    const float* qbase = q + (batch * 512 + l0) * 64;   // block-uniform

    // ---- phase 1: thread t owns k-row t; 8 l-dots; q on the scalar pipe ----
    {
        const float4* krow = (const float4*)(k + (batch * 512 + t) * 64);
        float acc[8] = {0.f, 0.f, 0.f, 0.f, 0.f, 0.f, 0.f, 0.f};
        #pragma unroll
        for (int dc = 0; dc < 16; ++dc) {
            const float4 kv = krow[dc];                  // 1 KB/wave-instr
            #pragma unroll
            for (int l = 0; l < 8; ++l) {
                const float4 qv4 = ((const float4*)(qbase + l * 64))[dc]; // uniform -> s_load
                acc[l] += qv4.x * kv.x + qv4.y * kv.y + qv4.z * kv.z + qv4.w * kv.w;
            }
        }
        #pragma unroll
        for (int l = 0; l < 8; ++l) sc[l][t] = scale * acc[l];  // coalesced LDS
    }
    lds_barrier();

    // ---- phase 2: softmax over K=512; wave wv -> l=wv ----
    {
        float vv[8]; float mx = -1e30f;
        #pragma unroll
        for (int j = 0; j < 8; ++j) { vv[j] = sc[wv][lane + 64 * j]; mx = fmaxf(mx, vv[j]); }
        #pragma unroll
        for (int off = 32; off; off >>= 1) mx = fmaxf(mx, __shfl_xor(mx, off, 64));
        float s = 0.f;
        #pragma unroll
        for (int j = 0; j < 8; ++j) { vv[j] = __expf(vv[j] - mx); s += vv[j]; }
        #pragma unroll
        for (int off = 32; off; off >>= 1) s += __shfl_xor(s, off, 64);
        const float inv = 1.0f / s;
        #pragma unroll
        for (int j = 0; j < 8; ++j) sc[wv][lane + 64 * j] = vv[j] * inv;
    }
    lds_barrier();

    // ---- phase 3: tmp[l][n] = sum_k w[l][k]*vkc[b][k][n]; wave covers 64 k --
    {
        const float* vkcb = vkc + batch * 512 * 64;
        const int ksub = lane >> 4;
        const int n0 = (lane & 15) << 2;
        const int kbeg = wv << 6;
        float4 a[8];
        #pragma unroll
        for (int l = 0; l < 8; ++l) { a[l].x = 0.f; a[l].y = 0.f; a[l].z = 0.f; a[l].w = 0.f; }
        #pragma unroll
        for (int i = 0; i < 16; ++i) {
            const int kk = kbeg + (i << 2) + ksub;
            const float4 v4 = *(const float4*)(vkcb + kk * 64 + n0);  // 1 KB/instr
            #pragma unroll
            for (int l = 0; l < 8; ++l) {
                const float w = sc[l][kk];
                a[l].x += w * v4.x; a[l].y += w * v4.y;
                a[l].z += w * v4.z; a[l].w += w * v4.w;
            }
        }
        #pragma unroll
        for (int l = 0; l < 8; ++l) {
            a[l].x += __shfl_down(a[l].x, 32, 64); a[l].x += __shfl_down(a[l].x, 16, 64);
            a[l].y += __shfl_down(a[l].y, 32, 64); a[l].y += __shfl_down(a[l].y, 16, 64);
            a[l].z += __shfl_down(a[l].z, 32, 64); a[l].z += __shfl_down(a[l].z, 16, 64);
            a[l].w += __shfl_down(a[l].w, 32, 64); a[l].w += __shfl_down(a[l].w, 16, 64);
        }
        if (lane < 16) {
            #pragma unroll
            for (int l = 0; l < 8; ++l)
                *(float4*)&tp[wv][l][lane << 2] = a[l];
        }
    }
    lds_barrier();

    // ---- phase 4: reduce 8 wave partials into LDS tmp ----
    // tmp_s[wv] is written and read by wave wv only -> no barrier after.
    {
        float s = tp[0][wv][lane];
        #pragma unroll
        for (int w = 1; w < 8; ++w) s += tp[w][wv][lane];
        tmp_s[wv][lane] = s;    // tmp[l=wv][n=lane]
    }

    // ---- phase 5: wave wv -> row l0+wv: attn = vq.tmp -> residual + LN ----
    {
        const int n0 = (lane & 15) << 2;
        const float4 t4 = *(const float4*)&tmp_s[wv][n0];

        #pragma unroll
        for (int it = 0; it < 16; ++it) {
            float part = v[it].x * t4.x + v[it].y * t4.y + v[it].z * t4.z + v[it].w * t4.w;
            part += __shfl_down(part, 8, 16);
            part += __shfl_down(part, 4, 16);
            part += __shfl_down(part, 2, 16);
            part += __shfl_down(part, 1, 16);
            if ((lane & 15) == 0) attn_s[wv][it * 4 + (lane >> 4)] = part;
        }
        // attn_s[wv] produced+consumed by the same wave -> no block barrier

        const float x = qv + attn_s[wv][lane];
        float s1 = x, s2 = x * x;
        #pragma unroll
        for (int off = 32; off; off >>= 1) {
            s1 += __shfl_xor(s1, off, 64);
            s2 += __shfl_xor(s2, off, 64);
        }
        const float mean = s1 * (1.0f / 64.0f);
        const float var = s2 * (1.0f / 64.0f) - mean * mean;
        const float r = rsqrtf(var + 1e-3f);
        out[row * 64 + lane] = (x - mean) * r * gamma[lane] + beta[lane];
    }
}

extern "C" void kernel_launch(void* const* d_in, const int* in_sizes, int n_in,
                              void* d_out, int out_size, void* d_ws, size_t ws_size,
                              hipStream_t stream) {
    const float* q     = (const float*)d_in[0];
    const float* k     = (const float*)d_in[1];
    const float* vq    = (const float*)d_in[2];
    const float* vk    = (const float*)d_in[3];
    const float* vexp  = (const float*)d_in[4];
    const float* scale = (const float*)d_in[5];
    const float* gamma = (const float*)d_in[6];
    const float* beta  = (const float*)d_in[7];
    float* out = (float*)d_out;

    float* vkc = (float*)d_ws;                 // 1 MB

    vkc_kernel<<<1024, 256, 0, stream>>>(vk, vexp, vkc);
    score_out_kernel<<<512, 512, 0, stream>>>(q, k, vkc, scale, vq, gamma, beta, out);
}

// Round 3
// 174.988 us; speedup vs baseline: 1.1048x; 1.1048x over previous
//
#include <hip/hip_runtime.h>

// B=8, L=512, K=512, D=M=N=P=64, all fp32.
// ws: vkc = 8*512*64 floats (1 MB).

// ---------------------------------------------------------------------------
// K1 (proven, ~6.2 TB/s): vkc[b,k,n] = sum_p vk[b,k,p,n] * vexp[b,k,p]
// ---------------------------------------------------------------------------
__global__ __launch_bounds__(256) void vkc_kernel(const float* __restrict__ vk,
                                                  const float* __restrict__ vexp,
                                                  float* __restrict__ vkc) {
    const int wave = (blockIdx.x << 2) + (threadIdx.x >> 6);  // b*512 + k
    const int lane = threadIdx.x & 63;

    const float ve_reg = vexp[wave * 64 + lane];
    const int n0 = (lane & 15) << 2;
    const float* base = vk + (long)wave * 4096;

    float ax = 0.f, ay = 0.f, az = 0.f, aw = 0.f;
    #pragma unroll
    for (int it = 0; it < 16; ++it) {
        const int p = (lane >> 4) + (it << 2);
        const float4 v4 = *(const float4*)(base + p * 64 + n0);
        const float w = __shfl(ve_reg, p, 64);
        ax += v4.x * w; ay += v4.y * w; az += v4.z * w; aw += v4.w * w;
    }
    ax += __shfl_down(ax, 32, 64); ax += __shfl_down(ax, 16, 64);
    ay += __shfl_down(ay, 32, 64); ay += __shfl_down(ay, 16, 64);
    az += __shfl_down(az, 32, 64); az += __shfl_down(az, 16, 64);
    aw += __shfl_down(aw, 32, 64); aw += __shfl_down(aw, 16, 64);

    if ((lane & 48) == 0) {
        float4 r; r.x = ax; r.y = ay; r.z = az; r.w = aw;
        *(float4*)(vkc + wave * 64 + n0) = r;
    }
}

// LDS-only barrier: drain LDS (lgkmcnt) but keep global loads (vmcnt) in
// flight across the barrier. All inter-phase deps below are LDS-only.
// The "memory" clobber also pins memory ops on their side of the fence,
// so issue-early loads cannot be sunk past it by the scheduler.
__device__ __forceinline__ void lds_barrier() {
    asm volatile("s_waitcnt lgkmcnt(0)" ::: "memory");
    __builtin_amdgcn_s_barrier();
}

// ---------------------------------------------------------------------------
// K2+K3 fused: per (batch, 8 l-rows), 512 threads:
//   scores -> softmax -> [tmp partials || issue vq loads] -> tmp (LDS)
//   -> vq.tmp -> residual + LN -> out
// vq loads are issued INSIDE phase 3 (one per iteration): they cross only
// one lgkmcnt-only barrier before phase-5 consumption, so their HBM latency
// hides under phase-3 FMAs + phase-4 LDS reduce, and the live range is short
// enough to avoid the round-2 spill (no launch_bounds VGPR cap this time).
// ---------------------------------------------------------------------------
__global__ __launch_bounds__(512) void score_out_kernel(
        const float* __restrict__ q,
        const float* __restrict__ k,
        const float* __restrict__ vkc,
        const float* __restrict__ scale_p,
        const float* __restrict__ vq,
        const float* __restrict__ gamma,
        const float* __restrict__ beta,
        float* __restrict__ out) {
    __shared__ float sc[8][512];          // 16 KB
    __shared__ float tp[8][8][64];        // 16 KB
    __shared__ float tmp_s[8][64];        // 2 KB
    __shared__ float attn_s[8][64];       // 2 KB

    const int t = threadIdx.x;
    const int wv = t >> 6;
    const int lane = t & 63;
    const int batch = blockIdx.x >> 6;
    const int l0 = (blockIdx.x & 63) << 3;

    const int row = batch * 512 + l0 + wv;         // this wave's output row
    const float qv = q[row * 64 + lane];           // residual (1 VGPR, cheap)

    const float scale = scale_p[0];
    const float* qbase = q + (batch * 512 + l0) * 64;   // block-uniform

    // ---- phase 1: thread t owns k-row t; 8 l-dots; q on the scalar pipe ----
    {
        const float4* krow = (const float4*)(k + (batch * 512 + t) * 64);
        float acc[8] = {0.f, 0.f, 0.f, 0.f, 0.f, 0.f, 0.f, 0.f};
        #pragma unroll
        for (int dc = 0; dc < 16; ++dc) {
            const float4 kv = krow[dc];                  // 1 KB/wave-instr
            #pragma unroll
            for (int l = 0; l < 8; ++l) {
                const float4 qv4 = ((const float4*)(qbase + l * 64))[dc]; // uniform -> s_load
                acc[l] += qv4.x * kv.x + qv4.y * kv.y + qv4.z * kv.z + qv4.w * kv.w;
            }
        }
        #pragma unroll
        for (int l = 0; l < 8; ++l) sc[l][t] = scale * acc[l];  // coalesced LDS
    }
    lds_barrier();

    // ---- phase 2: softmax over K=512; wave wv -> l=wv ----
    {
        float vv[8]; float mx = -1e30f;
        #pragma unroll
        for (int j = 0; j < 8; ++j) { vv[j] = sc[wv][lane + 64 * j]; mx = fmaxf(mx, vv[j]); }
        #pragma unroll
        for (int off = 32; off; off >>= 1) mx = fmaxf(mx, __shfl_xor(mx, off, 64));
        float s = 0.f;
        #pragma unroll
        for (int j = 0; j < 8; ++j) { vv[j] = __expf(vv[j] - mx); s += vv[j]; }
        #pragma unroll
        for (int off = 32; off; off >>= 1) s += __shfl_xor(s, off, 64);
        const float inv = 1.0f / s;
        #pragma unroll
        for (int j = 0; j < 8; ++j) sc[wv][lane + 64 * j] = vv[j] * inv;
    }
    lds_barrier();

    // ---- phase 3: tmp partials over this wave's 64 k; vq loads interleaved --
    float4 v[16];                                   // phase-5 operand (issue-early)
    const float* vql = vq + (long)row * 4096;
    {
        const float* vkcb = vkc + batch * 512 * 64;
        const int ksub = lane >> 4;
        const int n0 = (lane & 15) << 2;
        const int kbeg = wv << 6;
        float4 a[8];
        #pragma unroll
        for (int l = 0; l < 8; ++l) { a[l].x = 0.f; a[l].y = 0.f; a[l].z = 0.f; a[l].w = 0.f; }
        #pragma unroll
        for (int i = 0; i < 16; ++i) {
            v[i] = *(const float4*)(vql + i * 256 + lane * 4);   // T14 issue-early
            const int kk = kbeg + (i << 2) + ksub;
            const float4 v4 = *(const float4*)(vkcb + kk * 64 + n0);  // 1 KB/instr
            #pragma unroll
            for (int l = 0; l < 8; ++l) {
                const float w = sc[l][kk];
                a[l].x += w * v4.x; a[l].y += w * v4.y;
                a[l].z += w * v4.z; a[l].w += w * v4.w;
            }
        }
        #pragma unroll
        for (int l = 0; l < 8; ++l) {
            a[l].x += __shfl_down(a[l].x, 32, 64); a[l].x += __shfl_down(a[l].x, 16, 64);
            a[l].y += __shfl_down(a[l].y, 32, 64); a[l].y += __shfl_down(a[l].y, 16, 64);
            a[l].z += __shfl_down(a[l].z, 32, 64); a[l].z += __shfl_down(a[l].z, 16, 64);
            a[l].w += __shfl_down(a[l].w, 32, 64); a[l].w += __shfl_down(a[l].w, 16, 64);
        }
        if (lane < 16) {
            #pragma unroll
            for (int l = 0; l < 8; ++l)
                *(float4*)&tp[wv][l][lane << 2] = a[l];
        }
    }
    lds_barrier();

    // ---- phase 4: reduce 8 wave partials into LDS tmp ----
    // tmp_s[wv] is written and read by wave wv only -> no barrier after.
    {
        float s = tp[0][wv][lane];
        #pragma unroll
        for (int w = 1; w < 8; ++w) s += tp[w][wv][lane];
        tmp_s[wv][lane] = s;    // tmp[l=wv][n=lane]
    }

    // ---- phase 5: wave wv -> row l0+wv: attn = vq.tmp -> residual + LN ----
    {
        const int n0 = (lane & 15) << 2;
        const float4 t4 = *(const float4*)&tmp_s[wv][n0];

        #pragma unroll
        for (int it = 0; it < 16; ++it) {
            float part = v[it].x * t4.x + v[it].y * t4.y + v[it].z * t4.z + v[it].w * t4.w;
            part += __shfl_down(part, 8, 16);
            part += __shfl_down(part, 4, 16);
            part += __shfl_down(part, 2, 16);
            part += __shfl_down(part, 1, 16);
            if ((lane & 15) == 0) attn_s[wv][it * 4 + (lane >> 4)] = part;
        }
        // attn_s[wv] produced+consumed by the same wave -> no block barrier

        const float x = qv + attn_s[wv][lane];
        float s1 = x, s2 = x * x;
        #pragma unroll
        for (int off = 32; off; off >>= 1) {
            s1 += __shfl_xor(s1, off, 64);
            s2 += __shfl_xor(s2, off, 64);
        }
        const float mean = s1 * (1.0f / 64.0f);
        const float var = s2 * (1.0f / 64.0f) - mean * mean;
        const float r = rsqrtf(var + 1e-3f);
        out[row * 64 + lane] = (x - mean) * r * gamma[lane] + beta[lane];
    }
}

extern "C" void kernel_launch(void* const* d_in, const int* in_sizes, int n_in,
                              void* d_out, int out_size, void* d_ws, size_t ws_size,
                              hipStream_t stream) {
    const float* q     = (const float*)d_in[0];
    const float* k     = (const float*)d_in[1];
    const float* vq    = (const float*)d_in[2];
    const float* vk    = (const float*)d_in[3];
    const float* vexp  = (const float*)d_in[4];
    const float* scale = (const float*)d_in[5];
    const float* gamma = (const float*)d_in[6];
    const float* beta  = (const float*)d_in[7];
    float* out = (float*)d_out;

    float* vkc = (float*)d_ws;                 // 1 MB

    vkc_kernel<<<1024, 256, 0, stream>>>(vk, vexp, vkc);
    score_out_kernel<<<512, 512, 0, stream>>>(q, k, vkc, scale, vq, gamma, beta, out);
}